// Round 1
// baseline (25.697 us; speedup 1.0000x reference)
//
#include <hip/hip_runtime.h>
#include <math.h>

// Problem dims (fixed by reference setup_inputs):
//   x   : (NS=1024, NN=192) f32, values in {-1,+1}
//   W2  : (DD=24)           f32
//   W3  : (DD, DD)          f32
//   phi : (NN, 2)           f32
//   nd  : (NN, NN)          i32, values in [0, DD)
// out  : (NS,) f32 = J2 + J3 + logmf
//
// Math: c[j,r] = sum_i x_i * [nd[i,j]==r]  (per-sample column histogram)
//   J2 = 0.5 * sum_j x_j * dot(c_j, W2)
//   J3 =       sum_j x_j * (c_j^T W3 c_j)
//   logmf = sum_j log(phi[j, x_j>0 ? 1 : 0])

#define NS   1024
#define NN   192
#define DD   24
#define CPAD 25   // pad histogram rows to 25 floats: odd stride spreads banks

__global__ __launch_bounds__(NN) void jmf3_kernel(
    const float* __restrict__ x,    // (NS, NN)
    const float* __restrict__ W2,   // (DD)
    const float* __restrict__ W3,   // (DD, DD)
    const float* __restrict__ phi,  // (NN, 2)
    const int*   __restrict__ nd,   // (NN, NN)
    float* __restrict__ out)        // (NS)
{
    __shared__ float sx[NN];
    __shared__ float sW3[DD * DD];
    __shared__ float sW2[DD];
    __shared__ float sc[NN * CPAD];
    __shared__ float red[3];

    const int tid = threadIdx.x;   // 0..191
    const int n   = blockIdx.x;    // sample

    // ---- stage inputs ----
    sx[tid] = x[n * NN + tid];
    sW3[tid]       = W3[tid];
    sW3[tid + 192] = W3[tid + 192];
    sW3[tid + 384] = W3[tid + 384];
    if (tid < DD) sW2[tid] = W2[tid];
    #pragma unroll
    for (int r = 0; r < CPAD; ++r) sc[tid * CPAD + r] = 0.0f;
    __syncthreads();

    // ---- per-column histogram: thread tid owns column j = tid ----
    const int j = tid;
    float* cj = &sc[j * CPAD];
    for (int i = 0; i < NN; ++i) {
        int r = nd[i * NN + j];     // coalesced across lanes (contiguous j)
        cj[r] += sx[i];             // sx[i] is a broadcast read (free)
    }
    // each thread touched only its own row -> no barrier needed

    float c[DD];
    #pragma unroll
    for (int r = 0; r < DD; ++r) c[r] = cj[r];

    // ---- quadratic form q = c^T W3 c and l2 = dot(c, W2) ----
    float q = 0.0f, l2 = 0.0f;
    #pragma unroll
    for (int r = 0; r < DD; ++r) {
        float t = 0.0f;
        #pragma unroll
        for (int s = 0; s < DD; ++s) t = fmaf(sW3[r * DD + s], c[s], t);
        q  = fmaf(c[r], t, q);
        l2 = fmaf(sW2[r], c[r], l2);
    }

    const float xj  = sx[j];
    const int   idx = (xj > 0.0f) ? 1 : 0;
    float contrib = xj * (0.5f * l2 + q) + logf(phi[j * 2 + idx]);

    // ---- block reduction: 3 waves of 64 ----
    #pragma unroll
    for (int off = 32; off >= 1; off >>= 1)
        contrib += __shfl_down(contrib, off, 64);
    const int wave = tid >> 6;
    if ((tid & 63) == 0) red[wave] = contrib;
    __syncthreads();
    if (tid == 0) out[n] = red[0] + red[1] + red[2];
}

extern "C" void kernel_launch(void* const* d_in, const int* in_sizes, int n_in,
                              void* d_out, int out_size, void* d_ws, size_t ws_size,
                              hipStream_t stream) {
    const float* x   = (const float*)d_in[0];
    const float* W2  = (const float*)d_in[1];
    const float* W3  = (const float*)d_in[2];
    const float* phi = (const float*)d_in[3];
    const int*   nd  = (const int*)d_in[4];
    float* out = (float*)d_out;

    const int ns = in_sizes[0] / NN;   // 1024
    jmf3_kernel<<<ns, NN, 0, stream>>>(x, W2, W3, phi, nd, out);
}